// Round 2
// baseline (285.181 us; speedup 1.0000x reference)
//
#include <hip/hip_runtime.h>

// Conv-TasNet Decoder:
//   frames[b,k,l] = sum_n mixture_w[b,n,k]*est_mask[b,n,k]*W[l,n]
//   out = overlap_and_add(frames, 8);  T = 8*(K-1)+16 = 128008
//
// Memory-bound: 262 MB input stream -> ~42 us floor at 6.3 TB/s.
// Design:
//  - lane -> 2 consecutive k (float2 loads, 8B/lane, coalesced 512B/wave)
//  - 8 waves/block split N 8 ways (64 n each) -> 4000 waves total
//  - W transposed in LDS, broadcast float4 reads (wave-uniform n)
//  - cross-wave reduce via LDS in 2 l-halves; scratch UNIONed with Wt
//  - overlap-add identity: out[8k+l] += frames[k][l] for l in [0,16);
//    interior combined in LDS (plain float4 stores), block-boundary
//    8-float strips via atomicAdd onto memset-zeroed output.

#define B_ 4
#define N_ 512
#define K_ 16000
#define L_ 16
#define T_ 128008          // 8*(K_-1)+16
#define KPB 128            // k-columns per block (64 lanes x 2)
#define BLOCKS_PER_B 125   // K_/KPB
#define NWAVES 8
#define NCHUNK 64          // N_/NWAVES
#define RST 20             // red row stride (floats): f4-aligned, bank-spread
#define FST 20             // frames row stride

__global__ __launch_bounds__(512) void decoder_kernel(
    const float* __restrict__ mw, const float* __restrict__ em,
    const float* __restrict__ W, float* __restrict__ out) {
  // smemA: Wt[512][16] (32KB) during compute, then red[512][RST] (40KB)
  __shared__ float smemA[512 * RST];      // 40.0 KB
  __shared__ float framesS[KPB * FST];    // 10.0 KB
  float (*Wt)[L_] = (float(*)[L_])smemA;

  const int tid = threadIdx.x;

  // stage W transposed: Wt[n][l] = W[l*N_+n]
  for (int idx = tid; idx < L_ * N_; idx += 512) {
    int l = idx >> 9;        // / N_
    int n = idx & (N_ - 1);  // % N_
    Wt[n][l] = W[idx];
  }
  __syncthreads();

  const int w  = tid >> 6;                        // wave id -> n-chunk
  const int kl = tid & 63;                        // lane
  const int b  = blockIdx.x / BLOCKS_PER_B;
  const int kb = (blockIdx.x % BLOCKS_PER_B) * KPB;
  const int k0 = kb + 2 * kl;                     // this thread: k0, k0+1
  const int n0 = w * NCHUNK;

  const size_t base = (size_t)b * N_ * K_ + (size_t)n0 * K_ + k0;
  const float2* pm = reinterpret_cast<const float2*>(mw + base);
  const float2* pe = reinterpret_cast<const float2*>(em + base);

  float a0[L_], a1[L_];
  #pragma unroll
  for (int l = 0; l < L_; ++l) { a0[l] = 0.f; a1[l] = 0.f; }

  #pragma unroll 4
  for (int i = 0; i < NCHUNK; ++i) {
    const size_t off = (size_t)i * (K_ / 2);
    float2 m = pm[off];
    float2 e = pe[off];
    float p0 = m.x * e.x;
    float p1 = m.y * e.y;
    const float4* wv = reinterpret_cast<const float4*>(&Wt[n0 + i][0]);
    float4 w0 = wv[0], w1 = wv[1], w2 = wv[2], w3 = wv[3];
    a0[0]  += p0 * w0.x;  a1[0]  += p1 * w0.x;
    a0[1]  += p0 * w0.y;  a1[1]  += p1 * w0.y;
    a0[2]  += p0 * w0.z;  a1[2]  += p1 * w0.z;
    a0[3]  += p0 * w0.w;  a1[3]  += p1 * w0.w;
    a0[4]  += p0 * w1.x;  a1[4]  += p1 * w1.x;
    a0[5]  += p0 * w1.y;  a1[5]  += p1 * w1.y;
    a0[6]  += p0 * w1.z;  a1[6]  += p1 * w1.z;
    a0[7]  += p0 * w1.w;  a1[7]  += p1 * w1.w;
    a0[8]  += p0 * w2.x;  a1[8]  += p1 * w2.x;
    a0[9]  += p0 * w2.y;  a1[9]  += p1 * w2.y;
    a0[10] += p0 * w2.z;  a1[10] += p1 * w2.z;
    a0[11] += p0 * w2.w;  a1[11] += p1 * w2.w;
    a0[12] += p0 * w3.x;  a1[12] += p1 * w3.x;
    a0[13] += p0 * w3.y;  a1[13] += p1 * w3.y;
    a0[14] += p0 * w3.z;  a1[14] += p1 * w3.z;
    a0[15] += p0 * w3.w;  a1[15] += p1 * w3.w;
  }

  __syncthreads();  // Wt dead; smemA becomes red[512][RST]
  float* redS = smemA;

  // two reduction rounds over l-halves (lo = 0, then 8)
  #pragma unroll
  for (int round = 0; round < 2; ++round) {
    const int lo = round * 8;
    // each thread stores 16 partials: [kk*8 + l'] for l' in [0,8)
    {
      float* myrow = &redS[tid * RST];
      *reinterpret_cast<float4*>(myrow + 0)  =
          make_float4(a0[lo + 0], a0[lo + 1], a0[lo + 2], a0[lo + 3]);
      *reinterpret_cast<float4*>(myrow + 4)  =
          make_float4(a0[lo + 4], a0[lo + 5], a0[lo + 6], a0[lo + 7]);
      *reinterpret_cast<float4*>(myrow + 8)  =
          make_float4(a1[lo + 0], a1[lo + 1], a1[lo + 2], a1[lo + 3]);
      *reinterpret_cast<float4*>(myrow + 12) =
          make_float4(a1[lo + 4], a1[lo + 5], a1[lo + 6], a1[lo + 7]);
    }
    __syncthreads();
    // 256 reducers: column c = tid>>1 in [0,128), seg = tid&1 (float4 within 8)
    if (tid < 256) {
      const int c = tid >> 1, seg = tid & 1;
      const int kls = c >> 1, kk = c & 1;
      float4 s = make_float4(0.f, 0.f, 0.f, 0.f);
      #pragma unroll
      for (int ww = 0; ww < NWAVES; ++ww) {
        const float* row = &redS[(ww * 64 + kls) * RST];
        float4 v = *reinterpret_cast<const float4*>(row + kk * 8 + seg * 4);
        s.x += v.x; s.y += v.y; s.z += v.z; s.w += v.w;
      }
      *reinterpret_cast<float4*>(&framesS[c * FST + lo + seg * 4]) = s;
    }
    __syncthreads();  // red free for next round / frames visible at end
  }

  // overlap-add: out[8k + l] += frames[k][l], l in [0,16)
  // interior combined via LDS; boundary strips via atomics.
  if (tid < KPB) {
    const int c = tid;
    float* ob = out + (size_t)b * T_ + 8 * (size_t)(kb + c);
    const float* fc = &framesS[c * FST];
    float4 lo0 = *reinterpret_cast<const float4*>(fc + 0);  // l 0..3
    float4 lo1 = *reinterpret_cast<const float4*>(fc + 4);  // l 4..7
    if (c == 0) {
      atomicAdd(&ob[0], lo0.x); atomicAdd(&ob[1], lo0.y);
      atomicAdd(&ob[2], lo0.z); atomicAdd(&ob[3], lo0.w);
      atomicAdd(&ob[4], lo1.x); atomicAdd(&ob[5], lo1.y);
      atomicAdd(&ob[6], lo1.z); atomicAdd(&ob[7], lo1.w);
    } else {
      const float* fp = fc - FST;  // frames[c-1]
      float4 hi0 = *reinterpret_cast<const float4*>(fp + 8);
      float4 hi1 = *reinterpret_cast<const float4*>(fp + 12);
      float4 r0 = make_float4(lo0.x + hi0.x, lo0.y + hi0.y,
                              lo0.z + hi0.z, lo0.w + hi0.w);
      float4 r1 = make_float4(lo1.x + hi1.x, lo1.y + hi1.y,
                              lo1.z + hi1.z, lo1.w + hi1.w);
      *reinterpret_cast<float4*>(ob + 0) = r0;
      *reinterpret_cast<float4*>(ob + 4) = r1;
    }
    if (c == KPB - 1) {  // right boundary strip -> next block's region / tail
      float4 hi0 = *reinterpret_cast<const float4*>(fc + 8);
      float4 hi1 = *reinterpret_cast<const float4*>(fc + 12);
      atomicAdd(&ob[8],  hi0.x); atomicAdd(&ob[9],  hi0.y);
      atomicAdd(&ob[10], hi0.z); atomicAdd(&ob[11], hi0.w);
      atomicAdd(&ob[12], hi1.x); atomicAdd(&ob[13], hi1.y);
      atomicAdd(&ob[14], hi1.z); atomicAdd(&ob[15], hi1.w);
    }
  }
}

extern "C" void kernel_launch(void* const* d_in, const int* in_sizes, int n_in,
                              void* d_out, int out_size, void* d_ws, size_t ws_size,
                              hipStream_t stream) {
  const float* mw = (const float*)d_in[0];
  const float* em = (const float*)d_in[1];
  const float* W  = (const float*)d_in[2];
  float* out = (float*)d_out;

  // output is re-poisoned 0xAA before every timed launch; zero it (atomics add)
  hipMemsetAsync(out, 0, (size_t)out_size * sizeof(float), stream);

  decoder_kernel<<<B_ * BLOCKS_PER_B, 512, 0, stream>>>(mw, em, W, out);
}

// Round 3
// 280.479 us; speedup vs baseline: 1.0168x; 1.0168x over previous
//
#include <hip/hip_runtime.h>

// Conv-TasNet Decoder:
//   frames[b,k,l] = sum_n mixture_w[b,n,k]*est_mask[b,n,k]*W[l,n]
//   out = overlap_and_add(frames, 8);  T = 8*(K-1)+16 = 128008
//
// Memory-bound: 262 MB input stream -> ~42 us floor at 6.3 TB/s.
// R2 result: 110 us, latency-bound (VGPR=44 -> no loads in flight).
// R3 change: explicit A/B double-buffered prefetch of 4 n-rows (8 float2
// loads = 4 KB/wave in flight during each compute phase).

#define B_ 4
#define N_ 512
#define K_ 16000
#define L_ 16
#define T_ 128008          // 8*(K_-1)+16
#define KPB 128            // k-columns per block (64 lanes x 2)
#define BLOCKS_PER_B 125   // K_/KPB
#define NWAVES 8
#define NCHUNK 64          // N_/NWAVES (n-rows per wave)
#define RST 20             // red row stride (floats): f4-aligned, bank-spread
#define FST 20             // frames row stride

__global__ __launch_bounds__(512) void decoder_kernel(
    const float* __restrict__ mw, const float* __restrict__ em,
    const float* __restrict__ W, float* __restrict__ out) {
  // smemA: Wt[512][16] (32KB) during compute, then red[512][RST] (40KB)
  __shared__ float smemA[512 * RST];      // 40.0 KB
  __shared__ float framesS[KPB * FST];    // 10.0 KB
  float (*Wt)[L_] = (float(*)[L_])smemA;

  const int tid = threadIdx.x;

  // stage W transposed: Wt[n][l] = W[l*N_+n]
  for (int idx = tid; idx < L_ * N_; idx += 512) {
    int l = idx >> 9;        // / N_
    int n = idx & (N_ - 1);  // % N_
    Wt[n][l] = W[idx];
  }
  __syncthreads();

  const int w  = tid >> 6;                        // wave id -> n-chunk
  const int kl = tid & 63;                        // lane
  const int b  = blockIdx.x / BLOCKS_PER_B;
  const int kb = (blockIdx.x % BLOCKS_PER_B) * KPB;
  const int k0 = kb + 2 * kl;                     // this thread: k0, k0+1
  const int n0 = w * NCHUNK;

  const size_t rowF2 = K_ / 2;                    // float2 per n-row
  const size_t base = ((size_t)b * N_ + n0) * (size_t)K_ + k0;
  const float2* pm = reinterpret_cast<const float2*>(mw + base);
  const float2* pe = reinterpret_cast<const float2*>(em + base);

  float a0[L_], a1[L_];
  #pragma unroll
  for (int l = 0; l < L_; ++l) { a0[l] = 0.f; a1[l] = 0.f; }

  // chunk = 4 consecutive n-rows. 16 chunks. A/B register double-buffer.
  float2 mA[4], eA[4], mB[4], eB[4];

  auto loadChunk = [&](int cc, float2 (&dm)[4], float2 (&de)[4]) {
    const float2* qm = pm + (size_t)cc * 4 * rowF2;
    const float2* qe = pe + (size_t)cc * 4 * rowF2;
    #pragma unroll
    for (int j = 0; j < 4; ++j) {
      dm[j] = qm[(size_t)j * rowF2];
      de[j] = qe[(size_t)j * rowF2];
    }
  };
  auto computeChunk = [&](int cc, float2 (&dm)[4], float2 (&de)[4]) {
    #pragma unroll
    for (int j = 0; j < 4; ++j) {
      float p0 = dm[j].x * de[j].x;
      float p1 = dm[j].y * de[j].y;
      const float4* wv =
          reinterpret_cast<const float4*>(&Wt[n0 + cc * 4 + j][0]);
      float4 w0 = wv[0], w1 = wv[1], w2 = wv[2], w3 = wv[3];
      a0[0]  += p0 * w0.x;  a1[0]  += p1 * w0.x;
      a0[1]  += p0 * w0.y;  a1[1]  += p1 * w0.y;
      a0[2]  += p0 * w0.z;  a1[2]  += p1 * w0.z;
      a0[3]  += p0 * w0.w;  a1[3]  += p1 * w0.w;
      a0[4]  += p0 * w1.x;  a1[4]  += p1 * w1.x;
      a0[5]  += p0 * w1.y;  a1[5]  += p1 * w1.y;
      a0[6]  += p0 * w1.z;  a1[6]  += p1 * w1.z;
      a0[7]  += p0 * w1.w;  a1[7]  += p1 * w1.w;
      a0[8]  += p0 * w2.x;  a1[8]  += p1 * w2.x;
      a0[9]  += p0 * w2.y;  a1[9]  += p1 * w2.y;
      a0[10] += p0 * w2.z;  a1[10] += p1 * w2.z;
      a0[11] += p0 * w2.w;  a1[11] += p1 * w2.w;
      a0[12] += p0 * w3.x;  a1[12] += p1 * w3.x;
      a0[13] += p0 * w3.y;  a1[13] += p1 * w3.y;
      a0[14] += p0 * w3.z;  a1[14] += p1 * w3.z;
      a0[15] += p0 * w3.w;  a1[15] += p1 * w3.w;
    }
  };

  loadChunk(0, mA, eA);
  #pragma unroll 1
  for (int c = 0; c < NCHUNK / 4; c += 2) {
    loadChunk(c + 1, mB, eB);          // B in flight during compute(A)
    computeChunk(c, mA, eA);
    if (c + 2 < NCHUNK / 4) loadChunk(c + 2, mA, eA);  // A in flight
    computeChunk(c + 1, mB, eB);
  }

  __syncthreads();  // Wt dead; smemA becomes red[512][RST]
  float* redS = smemA;

  // two reduction rounds over l-halves (lo = 0, then 8)
  #pragma unroll
  for (int round = 0; round < 2; ++round) {
    const int lo = round * 8;
    {
      float* myrow = &redS[tid * RST];
      *reinterpret_cast<float4*>(myrow + 0)  =
          make_float4(a0[lo + 0], a0[lo + 1], a0[lo + 2], a0[lo + 3]);
      *reinterpret_cast<float4*>(myrow + 4)  =
          make_float4(a0[lo + 4], a0[lo + 5], a0[lo + 6], a0[lo + 7]);
      *reinterpret_cast<float4*>(myrow + 8)  =
          make_float4(a1[lo + 0], a1[lo + 1], a1[lo + 2], a1[lo + 3]);
      *reinterpret_cast<float4*>(myrow + 12) =
          make_float4(a1[lo + 4], a1[lo + 5], a1[lo + 6], a1[lo + 7]);
    }
    __syncthreads();
    // 256 reducers: column c = tid>>1 in [0,128), seg = tid&1
    if (tid < 256) {
      const int c = tid >> 1, seg = tid & 1;
      const int kls = c >> 1, kk = c & 1;
      float4 s = make_float4(0.f, 0.f, 0.f, 0.f);
      #pragma unroll
      for (int ww = 0; ww < NWAVES; ++ww) {
        const float* row = &redS[(ww * 64 + kls) * RST];
        float4 v = *reinterpret_cast<const float4*>(row + kk * 8 + seg * 4);
        s.x += v.x; s.y += v.y; s.z += v.z; s.w += v.w;
      }
      *reinterpret_cast<float4*>(&framesS[c * FST + lo + seg * 4]) = s;
    }
    __syncthreads();
  }

  // overlap-add: out[8k + l] += frames[k][l], l in [0,16)
  if (tid < KPB) {
    const int c = tid;
    float* ob = out + (size_t)b * T_ + 8 * (size_t)(kb + c);
    const float* fc = &framesS[c * FST];
    float4 lo0 = *reinterpret_cast<const float4*>(fc + 0);  // l 0..3
    float4 lo1 = *reinterpret_cast<const float4*>(fc + 4);  // l 4..7
    if (c == 0) {
      atomicAdd(&ob[0], lo0.x); atomicAdd(&ob[1], lo0.y);
      atomicAdd(&ob[2], lo0.z); atomicAdd(&ob[3], lo0.w);
      atomicAdd(&ob[4], lo1.x); atomicAdd(&ob[5], lo1.y);
      atomicAdd(&ob[6], lo1.z); atomicAdd(&ob[7], lo1.w);
    } else {
      const float* fp = fc - FST;  // frames[c-1]
      float4 hi0 = *reinterpret_cast<const float4*>(fp + 8);
      float4 hi1 = *reinterpret_cast<const float4*>(fp + 12);
      float4 r0 = make_float4(lo0.x + hi0.x, lo0.y + hi0.y,
                              lo0.z + hi0.z, lo0.w + hi0.w);
      float4 r1 = make_float4(lo1.x + hi1.x, lo1.y + hi1.y,
                              lo1.z + hi1.z, lo1.w + hi1.w);
      *reinterpret_cast<float4*>(ob + 0) = r0;
      *reinterpret_cast<float4*>(ob + 4) = r1;
    }
    if (c == KPB - 1) {  // right boundary strip
      float4 hi0 = *reinterpret_cast<const float4*>(fc + 8);
      float4 hi1 = *reinterpret_cast<const float4*>(fc + 12);
      atomicAdd(&ob[8],  hi0.x); atomicAdd(&ob[9],  hi0.y);
      atomicAdd(&ob[10], hi0.z); atomicAdd(&ob[11], hi0.w);
      atomicAdd(&ob[12], hi1.x); atomicAdd(&ob[13], hi1.y);
      atomicAdd(&ob[14], hi1.z); atomicAdd(&ob[15], hi1.w);
    }
  }
}

extern "C" void kernel_launch(void* const* d_in, const int* in_sizes, int n_in,
                              void* d_out, int out_size, void* d_ws, size_t ws_size,
                              hipStream_t stream) {
  const float* mw = (const float*)d_in[0];
  const float* em = (const float*)d_in[1];
  const float* W  = (const float*)d_in[2];
  float* out = (float*)d_out;

  // output is re-poisoned 0xAA before every timed launch; zero it (atomics add)
  hipMemsetAsync(out, 0, (size_t)out_size * sizeof(float), stream);

  decoder_kernel<<<B_ * BLOCKS_PER_B, 512, 0, stream>>>(mw, em, W, out);
}